// Round 5
// baseline (146.087 us; speedup 1.0000x reference)
//
#include <hip/hip_runtime.h>

// score[e] = dot(h[src[e]], h[dst[e]]), D=128, E=600k, N=100k.
// R5: XCD-sliced partial dot.
//  1) convert h -> bf16 (hb) in d_ws.
//  2) k_slice_dot: slice = blockIdx.x & 7 (rides round-robin block->XCD
//     dispatch). Each XCD reads only a 16-dim (32B) slice of every row ->
//     3.2MB working set, resident in its private 4MB L2. Partial dots to
//     partial[slice][e] (no atomics).
//  3) k_reduce: out[e] = sum over 8 slices.

#define SLICES 8

static __device__ __forceinline__ unsigned short f2bf(float x) {
    union { float f; unsigned u; } c; c.f = x;
    unsigned r = c.u + 0x7fffu + ((c.u >> 16) & 1u);
    return (unsigned short)(r >> 16);
}
static __device__ __forceinline__ float bf_lo(unsigned u) {
    union { unsigned u; float f; } c; c.u = u << 16; return c.f;
}
static __device__ __forceinline__ float bf_hi(unsigned u) {
    union { unsigned u; float f; } c; c.u = u & 0xffff0000u; return c.f;
}

__global__ void k_convert(const float* __restrict__ h, unsigned* __restrict__ hb,
                          long long n) {
    long long t = (long long)blockIdx.x * blockDim.x + threadIdx.x;
    if (t * 8 >= n) return;
    const float4* H4 = reinterpret_cast<const float4*>(h);
    float4 v0 = H4[t * 2];
    float4 v1 = H4[t * 2 + 1];
    uint4 o;
    o.x = (unsigned)f2bf(v0.x) | ((unsigned)f2bf(v0.y) << 16);
    o.y = (unsigned)f2bf(v0.z) | ((unsigned)f2bf(v0.w) << 16);
    o.z = (unsigned)f2bf(v1.x) | ((unsigned)f2bf(v1.y) << 16);
    o.w = (unsigned)f2bf(v1.z) | ((unsigned)f2bf(v1.w) << 16);
    reinterpret_cast<uint4*>(hb)[t] = o;
}

static __device__ __forceinline__ float dot8(uint4 a, uint4 b) {
    float v = 0.f;
    v = fmaf(bf_lo(a.x), bf_lo(b.x), v);
    v = fmaf(bf_hi(a.x), bf_hi(b.x), v);
    v = fmaf(bf_lo(a.y), bf_lo(b.y), v);
    v = fmaf(bf_hi(a.y), bf_hi(b.y), v);
    v = fmaf(bf_lo(a.z), bf_lo(b.z), v);
    v = fmaf(bf_hi(a.z), bf_hi(b.z), v);
    v = fmaf(bf_lo(a.w), bf_lo(b.w), v);
    v = fmaf(bf_hi(a.w), bf_hi(b.w), v);
    return v;
}

// Block = 256 threads = 128 pairs; each pair handles 4 edges (block: 512 edges).
// Thread (pair p, sub s) reads uint4 s of slice x of the row: 32B per row-slice.
__global__ void k_slice_dot(const uint4* __restrict__ hb,
                            const int* __restrict__ src,
                            const int* __restrict__ dst,
                            float* __restrict__ partial, int E) {
    const int slice = blockIdx.x & (SLICES - 1);
    const int chunk = blockIdx.x >> 3;
    const int pairId = threadIdx.x >> 1;
    const int sub = threadIdx.x & 1;

    const long long base = (long long)chunk * 512;
    const unsigned sliceOfs = (unsigned)slice * 2 + (unsigned)sub;   // uint4 units

    long long e0 = base + pairId;
    long long e1 = e0 + 128;
    long long e2 = e0 + 256;
    long long e3 = e0 + 384;

    bool v0ok = e0 < E, v1ok = e1 < E, v2ok = e2 < E, v3ok = e3 < E;

    int s0 = v0ok ? src[e0] : 0, d0 = v0ok ? dst[e0] : 0;
    int s1 = v1ok ? src[e1] : 0, d1 = v1ok ? dst[e1] : 0;
    int s2 = v2ok ? src[e2] : 0, d2 = v2ok ? dst[e2] : 0;
    int s3 = v3ok ? src[e3] : 0, d3 = v3ok ? dst[e3] : 0;

    // All 8 row-slice loads issued before use (MLP).
    uint4 a0 = hb[(size_t)s0 * 16 + sliceOfs];
    uint4 b0 = hb[(size_t)d0 * 16 + sliceOfs];
    uint4 a1 = hb[(size_t)s1 * 16 + sliceOfs];
    uint4 b1 = hb[(size_t)d1 * 16 + sliceOfs];
    uint4 a2 = hb[(size_t)s2 * 16 + sliceOfs];
    uint4 b2 = hb[(size_t)d2 * 16 + sliceOfs];
    uint4 a3 = hb[(size_t)s3 * 16 + sliceOfs];
    uint4 b3 = hb[(size_t)d3 * 16 + sliceOfs];

    float v0 = dot8(a0, b0);
    float v1 = dot8(a1, b1);
    float v2 = dot8(a2, b2);
    float v3 = dot8(a3, b3);

    // Pair sum (lanes 2k/2k+1 hold the two 8-dim halves of the 16-dim slice).
    v0 += __shfl_xor(v0, 1);
    v1 += __shfl_xor(v1, 1);
    v2 += __shfl_xor(v2, 1);
    v3 += __shfl_xor(v3, 1);

    if (sub == 0) {
        float* p = partial + (size_t)slice * E;
        if (v0ok) p[e0] = v0;
        if (v1ok) p[e1] = v1;
        if (v2ok) p[e2] = v2;
        if (v3ok) p[e3] = v3;
    }
}

__global__ void k_reduce(const float* __restrict__ partial,
                         float* __restrict__ out, int E) {
    int e = blockIdx.x * blockDim.x + threadIdx.x;
    if (e >= E) return;
    float s = 0.f;
    #pragma unroll
    for (int x = 0; x < SLICES; ++x) s += partial[(size_t)x * E + e];
    out[e] = s;
}

// ---- fallback: R4 edge-parallel bf16 gather ----
__global__ void edge_dot_bf16(const unsigned* __restrict__ hb,
                              const int* __restrict__ src,
                              const int* __restrict__ dst,
                              float* __restrict__ out, int E) {
    const int lane = threadIdx.x & 15;
    long long g = ((long long)blockIdx.x * blockDim.x + threadIdx.x) >> 4;
    if (g >= E) return;
    const uint4* __restrict__ H = reinterpret_cast<const uint4*>(hb);
    uint4 a = H[(size_t)src[g] * 16 + lane];
    uint4 b = H[(size_t)dst[g] * 16 + lane];
    float v = dot8(a, b);
    v += __shfl_xor(v, 8);
    v += __shfl_xor(v, 4);
    v += __shfl_xor(v, 2);
    v += __shfl_xor(v, 1);
    if (lane == 0) out[g] = v;
}

extern "C" void kernel_launch(void* const* d_in, const int* in_sizes, int n_in,
                              void* d_out, int out_size, void* d_ws, size_t ws_size,
                              hipStream_t stream) {
    const float* h   = (const float*)d_in[0];
    const int*   src = (const int*)d_in[1];
    const int*   dst = (const int*)d_in[2];
    float*       out = (float*)d_out;

    const long long nElem = in_sizes[0];   // N*128
    const int E = in_sizes[1];

    const int B = 256;
    size_t hbBytes = (size_t)nElem * 2;
    size_t partBytes = (size_t)SLICES * E * 4;

    if (ws_size >= hbBytes + partBytes) {
        unsigned* hb = (unsigned*)d_ws;
        float* partial = (float*)((char*)d_ws + hbBytes);

        long long nThreadsConv = nElem / 8;
        k_convert<<<(int)((nThreadsConv + B - 1) / B), B, 0, stream>>>(h, hb, nElem);

        int blocksPerSlice = (E + 511) / 512;
        k_slice_dot<<<blocksPerSlice * SLICES, B, 0, stream>>>(
            (const uint4*)hb, src, dst, partial, E);

        k_reduce<<<(E + B - 1) / B, B, 0, stream>>>(partial, out, E);
    } else if (ws_size >= hbBytes) {
        unsigned* hb = (unsigned*)d_ws;
        long long nThreadsConv = nElem / 8;
        k_convert<<<(int)((nThreadsConv + B - 1) / B), B, 0, stream>>>(h, hb, nElem);
        long long nThreads = (long long)E * 16;
        edge_dot_bf16<<<(int)((nThreads + B - 1) / B), B, 0, stream>>>(hb, src, dst, out, E);
    }
}

// Round 6
// 38.081 us; speedup vs baseline: 3.8362x; 3.8362x over previous
//
#include <hip/hip_runtime.h>

// score[e] = dot(h[src[e]], h[dst[e]]), D=128, E=600k, N=100k.
// R6: per-row-scaled int8 gather. Row = 128 int8 = exactly ONE 128B cache
// line (bf16 row was 2 lines). Quantize once (rowmax/127 scale), gather +
// v_dot4 int8 dot, rescale by s_src*s_dst. Error est ~0.5-1.0 absmax vs
// 3.26 threshold (bf16 measured 0.25).

static __device__ __forceinline__ int dot4i8(int a, int b, int c) {
#if __has_builtin(__builtin_amdgcn_sdot4)
    return __builtin_amdgcn_sdot4(a, b, c, false);
#else
    int r = c;
    r += (int)(signed char)(a)        * (int)(signed char)(b);
    r += (int)(signed char)(a >> 8)   * (int)(signed char)(b >> 8);
    r += (int)(signed char)(a >> 16)  * (int)(signed char)(b >> 16);
    r += (int)(signed char)(a >> 24)  * (int)(signed char)(b >> 24);
    return r;
#endif
}

// One 32-lane group per row: lane holds float4 (dims 4l..4l+3).
// rowmax via shfl reduce, quantize to int8, pack 4/dword, coalesced write.
__global__ void k_rowquant(const float* __restrict__ h,
                           unsigned* __restrict__ hq,
                           float* __restrict__ inv, int N) {
    const int lane = threadIdx.x & 31;
    int row = blockIdx.x * 8 + (threadIdx.x >> 5);
    if (row >= N) return;

    const float4* __restrict__ H4 = reinterpret_cast<const float4*>(h);
    float4 v = H4[(size_t)row * 32 + lane];

    float m = fmaxf(fmaxf(fabsf(v.x), fabsf(v.y)), fmaxf(fabsf(v.z), fabsf(v.w)));
    m = fmaxf(m, __shfl_xor(m, 16));
    m = fmaxf(m, __shfl_xor(m, 8));
    m = fmaxf(m, __shfl_xor(m, 4));
    m = fmaxf(m, __shfl_xor(m, 2));
    m = fmaxf(m, __shfl_xor(m, 1));

    float s  = (m > 1e-30f) ? 127.0f / m : 0.0f;
    float is = (m > 1e-30f) ? m / 127.0f : 0.0f;

    int q0 = __float2int_rn(v.x * s);
    int q1 = __float2int_rn(v.y * s);
    int q2 = __float2int_rn(v.z * s);
    int q3 = __float2int_rn(v.w * s);

    unsigned p = (unsigned)(q0 & 0xff) | ((unsigned)(q1 & 0xff) << 8) |
                 ((unsigned)(q2 & 0xff) << 16) | ((unsigned)(q3 & 0xff) << 24);
    hq[(size_t)row * 32 + lane] = p;

    if (lane == 0) inv[row] = is;
}

// 8 lanes per edge; lane reads one uint4 (16 int8) of src row + dst row.
__global__ void k_edge_dot_i8(const uint4* __restrict__ hq,
                              const float* __restrict__ inv,
                              const int* __restrict__ src,
                              const int* __restrict__ dst,
                              float* __restrict__ out, int E) {
    const int lane = threadIdx.x & 7;
    long long g = ((long long)blockIdx.x * blockDim.x + threadIdx.x) >> 3;
    if (g >= E) return;

    size_t s = (size_t)src[g];
    size_t d = (size_t)dst[g];

    uint4 a = hq[s * 8 + lane];
    uint4 b = hq[d * 8 + lane];

    int idot = 0;
    idot = dot4i8((int)a.x, (int)b.x, idot);
    idot = dot4i8((int)a.y, (int)b.y, idot);
    idot = dot4i8((int)a.z, (int)b.z, idot);
    idot = dot4i8((int)a.w, (int)b.w, idot);

    idot += __shfl_xor(idot, 4);
    idot += __shfl_xor(idot, 2);
    idot += __shfl_xor(idot, 1);

    if (lane == 0) {
        out[g] = (float)idot * inv[s] * inv[d];
    }
}

// ---- fallback: R4 bf16 path if workspace too small (not expected) ----
static __device__ __forceinline__ unsigned short f2bf(float x) {
    union { float f; unsigned u; } c; c.f = x;
    unsigned r = c.u + 0x7fffu + ((c.u >> 16) & 1u);
    return (unsigned short)(r >> 16);
}
static __device__ __forceinline__ float bf_lo(unsigned u) {
    union { unsigned u; float f; } c; c.u = u << 16; return c.f;
}
static __device__ __forceinline__ float bf_hi(unsigned u) {
    union { unsigned u; float f; } c; c.u = u & 0xffff0000u; return c.f;
}
__global__ void k_convert(const float* __restrict__ h, unsigned* __restrict__ hb,
                          long long n) {
    long long t = (long long)blockIdx.x * blockDim.x + threadIdx.x;
    if (t * 8 >= n) return;
    const float4* H4 = reinterpret_cast<const float4*>(h);
    float4 v0 = H4[t * 2];
    float4 v1 = H4[t * 2 + 1];
    uint4 o;
    o.x = (unsigned)f2bf(v0.x) | ((unsigned)f2bf(v0.y) << 16);
    o.y = (unsigned)f2bf(v0.z) | ((unsigned)f2bf(v0.w) << 16);
    o.z = (unsigned)f2bf(v1.x) | ((unsigned)f2bf(v1.y) << 16);
    o.w = (unsigned)f2bf(v1.z) | ((unsigned)f2bf(v1.w) << 16);
    reinterpret_cast<uint4*>(hb)[t] = o;
}
__global__ void edge_dot_bf16(const unsigned* __restrict__ hb,
                              const int* __restrict__ src,
                              const int* __restrict__ dst,
                              float* __restrict__ out, int E) {
    const int lane = threadIdx.x & 15;
    long long g = ((long long)blockIdx.x * blockDim.x + threadIdx.x) >> 4;
    if (g >= E) return;
    const uint4* __restrict__ H = reinterpret_cast<const uint4*>(hb);
    uint4 a = H[(size_t)src[g] * 16 + lane];
    uint4 b = H[(size_t)dst[g] * 16 + lane];
    float v = 0.f;
    v = fmaf(bf_lo(a.x), bf_lo(b.x), v);
    v = fmaf(bf_hi(a.x), bf_hi(b.x), v);
    v = fmaf(bf_lo(a.y), bf_lo(b.y), v);
    v = fmaf(bf_hi(a.y), bf_hi(b.y), v);
    v = fmaf(bf_lo(a.z), bf_lo(b.z), v);
    v = fmaf(bf_hi(a.z), bf_hi(b.z), v);
    v = fmaf(bf_lo(a.w), bf_lo(b.w), v);
    v = fmaf(bf_hi(a.w), bf_hi(b.w), v);
    v += __shfl_xor(v, 8);
    v += __shfl_xor(v, 4);
    v += __shfl_xor(v, 2);
    v += __shfl_xor(v, 1);
    if (lane == 0) out[g] = v;
}

extern "C" void kernel_launch(void* const* d_in, const int* in_sizes, int n_in,
                              void* d_out, int out_size, void* d_ws, size_t ws_size,
                              hipStream_t stream) {
    const float* h   = (const float*)d_in[0];
    const int*   src = (const int*)d_in[1];
    const int*   dst = (const int*)d_in[2];
    float*       out = (float*)d_out;

    const long long nElem = in_sizes[0];   // N*128
    const int N = (int)(nElem / 128);
    const int E = in_sizes[1];

    const int B = 256;
    size_t i8Bytes = (size_t)nElem + (size_t)N * 4;   // hq + inv

    if (ws_size >= i8Bytes) {
        unsigned* hq  = (unsigned*)d_ws;
        float*    inv = (float*)((char*)d_ws + (size_t)nElem);

        k_rowquant<<<(N + 7) / 8, B, 0, stream>>>(h, hq, inv, N);

        long long nThreads = (long long)E * 8;
        k_edge_dot_i8<<<(int)((nThreads + B - 1) / B), B, 0, stream>>>(
            (const uint4*)hq, inv, src, dst, out, E);
    } else if (ws_size >= (size_t)nElem * 2) {
        unsigned* hb = (unsigned*)d_ws;
        long long nThreadsConv = nElem / 8;
        k_convert<<<(int)((nThreadsConv + B - 1) / B), B, 0, stream>>>(h, hb, nElem);
        long long nThreads = (long long)E * 16;
        edge_dot_bf16<<<(int)((nThreads + B - 1) / B), B, 0, stream>>>(hb, src, dst, out, E);
    }
}